// Round 6
// baseline (95.866 us; speedup 1.0000x reference)
//
#include <hip/hip_runtime.h>

// Problem constants (match reference file)
#define Bn  4
#define Cn  3
#define Hn  224
#define Wn  224
#define Kn  196
#define En  768
#define HW  (Hn * Wn)            // 50176 pixels per (b,c) plane
#define BPB 49                   // pooling blocks per batch
#define NPOOL (Bn * BPB)         // 196 pooling blocks
#define KC  (Kn * Cn)            // 588 histogram slots
#define EPB 8                    // embed blocks per batch
#define NEMB (Bn * EPB)          // 32 embed blocks
#define KCH 25                   // k-chunk per embed block (last gets 21)
#define MAGIC 0x517C0DEu         // != 0xAAAAAAAA ws poison, != 0

// ws layout: partials (B,3,Kn,BPB) floats, then NPOOL uint tags.
// partials written scattered by producers, read as contiguous 49-float
// runs by consumers. Tags start poisoned (0xAA..) each call => != MAGIC.

// One dispatch, 228 blocks x 256 threads, all co-resident (<=256 CUs):
//   blocks [0,196): pooling producers (1024 px each, LDS histogram)
//   blocks [196,228): embed consumers (one (batch, 25-k chunk) each),
//     spin on the batch's 49 tags, then reduce + matmul + store.
__global__ __launch_bounds__(256) void fused_kernel(
    const float* __restrict__ img,       // (B,C,H,W)
    const int*   __restrict__ seg,       // (B,H,W)
    const float* __restrict__ Wm,        // (C,E)
    const float* __restrict__ bias,      // (E,)
    float*       __restrict__ out,       // (B,K,E)
    float*       __restrict__ ws)
{
    float*    partials = ws;                                  // (B,3,Kn,BPB)
    unsigned* tags = (unsigned*)(ws + (size_t)Bn * 3 * Kn * BPB);  // [NPOOL]
    const int tid = threadIdx.x;

    if (blockIdx.x < NPOOL) {
        // ---------------- producer: segmented partial sums ----------------
        __shared__ float sh[KC];
        const int batch = blockIdx.x / BPB;
        const int blk   = blockIdx.x % BPB;
        const int p4    = blk * 256 + tid;    // float4 index within a plane

        const int4*   seg4 = (const int4*)(seg + (size_t)batch * HW);
        const float4* im   = (const float4*)(img + (size_t)batch * Cn * HW);

        // loads first — latency overlaps LDS zero + barrier
        const int4   s  = seg4[p4];
        const float4 v0 = im[p4];
        const float4 v1 = im[HW / 4 + p4];
        const float4 v2 = im[2 * (HW / 4) + p4];

        if (tid < KC / 4) ((float4*)sh)[tid] = make_float4(0.f, 0.f, 0.f, 0.f);
        __syncthreads();

        atomicAdd(&sh[s.x * 3 + 0], v0.x);
        atomicAdd(&sh[s.x * 3 + 1], v1.x);
        atomicAdd(&sh[s.x * 3 + 2], v2.x);
        atomicAdd(&sh[s.y * 3 + 0], v0.y);
        atomicAdd(&sh[s.y * 3 + 1], v1.y);
        atomicAdd(&sh[s.y * 3 + 2], v2.y);
        atomicAdd(&sh[s.z * 3 + 0], v0.z);
        atomicAdd(&sh[s.z * 3 + 1], v1.z);
        atomicAdd(&sh[s.z * 3 + 2], v2.z);
        atomicAdd(&sh[s.w * 3 + 0], v0.w);
        atomicAdd(&sh[s.w * 3 + 1], v1.w);
        atomicAdd(&sh[s.w * 3 + 2], v2.w);
        __syncthreads();

        // transposed flush: sh[k*3+c] -> partials[((batch*3+c)*Kn+k)*BPB+blk]
        for (int i = tid; i < KC; i += 256) {
            const int k = i / 3;
            const int c = i % 3;
            partials[(((size_t)batch * 3 + c) * Kn + k) * BPB + blk] = sh[i];
        }
        __threadfence();          // release partials device-wide (cross-XCD)
        __syncthreads();          // all threads' stores fenced before tag
        if (tid == 0) atomicExch(&tags[blockIdx.x], MAGIC);
    } else {
        // ---------------- consumer: reduce + embed ----------------
        const int e     = blockIdx.x - NPOOL;   // 0..31
        const int batch = e / EPB;
        const int chunk = e % EPB;
        const int k0    = chunk * KCH;
        const int nk    = (Kn - k0 < KCH) ? (Kn - k0) : KCH;  // 25 or 21

        __shared__ float psum[KCH * 3];

        // spin until all 49 producers of this batch have published.
        // atomicAdd(p,0) is an RMW at the coherent point — cross-XCD safe.
        if (tid < BPB) {
            while (atomicAdd(&tags[batch * BPB + tid], 0u) != MAGIC) {}
        }
        __threadfence();          // acquire
        __syncthreads();

        // pooled[k,c] = sum_j partials[b,c,k,j]  (49 contiguous floats)
        if (tid < nk * 3) {
            const int kk = tid / 3;
            const int c  = tid % 3;
            const float* row =
                partials + (((size_t)batch * 3 + c) * Kn + (k0 + kk)) * BPB;
            float ssum = 0.0f;
            #pragma unroll
            for (int j = 0; j < BPB; ++j) ssum += row[j];
            psum[kk * 3 + c] = ssum * (1.0f / (float)HW);
        }
        __syncthreads();

        // out[b,k,e] = sum_c pooled[k,c]*W[c,e] + bias[e]; float4 stores
        for (int idx = tid; idx < nk * (En / 4); idx += 256) {
            const int kk = idx / (En / 4);
            const int e4 = idx % (En / 4);
            const float p0 = psum[kk * 3 + 0];
            const float p1 = psum[kk * 3 + 1];
            const float p2 = psum[kk * 3 + 2];

            const float4 w0 = ((const float4*)(Wm          ))[e4];
            const float4 w1 = ((const float4*)(Wm +     En ))[e4];
            const float4 w2 = ((const float4*)(Wm + 2 * En ))[e4];
            const float4 bb = ((const float4*)bias)[e4];

            float4 r;
            r.x = p0 * w0.x + p1 * w1.x + p2 * w2.x + bb.x;
            r.y = p0 * w0.y + p1 * w1.y + p2 * w2.y + bb.y;
            r.z = p0 * w0.z + p1 * w1.z + p2 * w2.z + bb.z;
            r.w = p0 * w0.w + p1 * w1.w + p2 * w2.w + bb.w;
            ((float4*)out)[(size_t)(batch * Kn + k0 + kk) * (En / 4) + e4] = r;
        }
    }
}

extern "C" void kernel_launch(void* const* d_in, const int* in_sizes, int n_in,
                              void* d_out, int out_size, void* d_ws, size_t ws_size,
                              hipStream_t stream) {
    const float* img  = (const float*)d_in[0];  // (4,3,224,224) fp32
    const int*   seg  = (const int*)  d_in[1];  // (4,224,224) int32
    const float* Wm   = (const float*)d_in[2];  // (3,768) fp32
    const float* bias = (const float*)d_in[3];  // (768,) fp32
    float* out = (float*)d_out;                 // (4,196,768) fp32
    float* ws  = (float*)d_ws;                  // partials + tags

    fused_kernel<<<NPOOL + NEMB, 256, 0, stream>>>(img, seg, Wm, bias, out, ws);
}

// Round 7
// 93.509 us; speedup vs baseline: 1.0252x; 1.0252x over previous
//
#include <hip/hip_runtime.h>

// Problem constants (match reference file)
#define Bn  4
#define Cn  3
#define Hn  224
#define Wn  224
#define Kn  196
#define En  768
#define HW  (Hn * Wn)            // 50176 pixels per (b,c) plane
#define BPB 49                   // pooling blocks per batch
#define NPOOL (Bn * BPB)         // 196 blocks total
#define KC  (Kn * Cn)            // 588 histogram slots
#define EPB 8                    // consumer blocks per batch (blk 0..7 continue)
#define KCH 25                   // k-chunk per consumer (last gets 21)
#define MAGIC 0x517C0DEu         // != 0xAAAAAAAA ws poison, != 0
#define TAGSTRIDE 16             // uints; one 64B line per tag (no false sharing)

// ws layout: partials (B,3,Kn,BPB) floats, then NPOOL tags padded to one
// cache line each. Tags are poisoned (0xAA..) by the harness before every
// call => != MAGIC at entry; graceful for any initial value != MAGIC.

// Single dispatch, 196 blocks x 256 threads (all co-resident, <= 256 CUs).
// Every block is a producer (1024 px LDS histogram -> partials + tag).
// Blocks with blk < EPB then CONTINUE as consumers for their own batch:
// throttled-poll the batch's 49 tags, reduce 49 partials/k, matmul, store.
__global__ __launch_bounds__(256) void fused_kernel(
    const float* __restrict__ img,       // (B,C,H,W)
    const int*   __restrict__ seg,       // (B,H,W)
    const float* __restrict__ Wm,        // (C,E)
    const float* __restrict__ bias,      // (E,)
    float*       __restrict__ out,       // (B,K,E)
    float*       __restrict__ ws)
{
    float*    partials = ws;                                      // (B,3,Kn,BPB)
    unsigned* tags = (unsigned*)(ws + (size_t)Bn * 3 * Kn * BPB); // NPOOL lines
    const int tid   = threadIdx.x;
    const int batch = blockIdx.x / BPB;
    const int blk   = blockIdx.x % BPB;

    // ---------------- producer: segmented partial sums ----------------
    __shared__ float sh[KC];
    __shared__ float psum[KCH * 3];
    {
        const int p4 = blk * 256 + tid;       // float4 index within a plane
        const int4*   seg4 = (const int4*)(seg + (size_t)batch * HW);
        const float4* im   = (const float4*)(img + (size_t)batch * Cn * HW);

        // loads first — latency overlaps LDS zero + barrier
        const int4   s  = seg4[p4];
        const float4 v0 = im[p4];
        const float4 v1 = im[HW / 4 + p4];
        const float4 v2 = im[2 * (HW / 4) + p4];

        if (tid < KC / 4) ((float4*)sh)[tid] = make_float4(0.f, 0.f, 0.f, 0.f);
        __syncthreads();

        atomicAdd(&sh[s.x * 3 + 0], v0.x);
        atomicAdd(&sh[s.x * 3 + 1], v1.x);
        atomicAdd(&sh[s.x * 3 + 2], v2.x);
        atomicAdd(&sh[s.y * 3 + 0], v0.y);
        atomicAdd(&sh[s.y * 3 + 1], v1.y);
        atomicAdd(&sh[s.y * 3 + 2], v2.y);
        atomicAdd(&sh[s.z * 3 + 0], v0.z);
        atomicAdd(&sh[s.z * 3 + 1], v1.z);
        atomicAdd(&sh[s.z * 3 + 2], v2.z);
        atomicAdd(&sh[s.w * 3 + 0], v0.w);
        atomicAdd(&sh[s.w * 3 + 1], v1.w);
        atomicAdd(&sh[s.w * 3 + 2], v2.w);
        __syncthreads();

        // transposed flush: sh[k*3+c] -> partials[((b*3+c)*Kn+k)*BPB+blk]
        for (int i = tid; i < KC; i += 256) {
            const int k = i / 3;
            const int c = i % 3;
            partials[(((size_t)batch * 3 + c) * Kn + k) * BPB + blk] = sh[i];
        }
        __threadfence();              // release partials device-wide
        __syncthreads();              // all lanes' stores fenced before tag
        if (tid == 0) atomicExch(&tags[(size_t)blockIdx.x * TAGSTRIDE], MAGIC);
    }

    // ---------------- consumer: first EPB blocks of each batch ----------
    if (blk >= EPB) return;

    const int k0 = blk * KCH;
    const int nk = (Kn - k0 < KCH) ? (Kn - k0) : KCH;   // 25 or 21

    // throttled poll: 49 lanes, one private cache line each, ~512cy period
    if (tid < BPB) {
        while (atomicAdd(&tags[(size_t)(batch * BPB + tid) * TAGSTRIDE], 0u)
               != MAGIC) {
            __builtin_amdgcn_s_sleep(8);
        }
    }
    __threadfence();                  // acquire
    __syncthreads();

    // pooled[k,c] = sum_j partials[b,c,k,j]  (49 contiguous floats)
    if (tid < nk * 3) {
        const int kk = tid / 3;
        const int c  = tid % 3;
        const float* row =
            partials + (((size_t)batch * 3 + c) * Kn + (k0 + kk)) * BPB;
        float ssum = 0.0f;
        #pragma unroll
        for (int j = 0; j < BPB; ++j) ssum += row[j];
        psum[kk * 3 + c] = ssum * (1.0f / (float)HW);
    }
    __syncthreads();

    // out[b,k,e] = sum_c pooled[k,c]*W[c,e] + bias[e]; float4 stores
    for (int idx = tid; idx < nk * (En / 4); idx += 256) {
        const int kk = idx / (En / 4);
        const int e4 = idx % (En / 4);
        const float p0 = psum[kk * 3 + 0];
        const float p1 = psum[kk * 3 + 1];
        const float p2 = psum[kk * 3 + 2];

        const float4 w0 = ((const float4*)(Wm          ))[e4];
        const float4 w1 = ((const float4*)(Wm +     En ))[e4];
        const float4 w2 = ((const float4*)(Wm + 2 * En ))[e4];
        const float4 bb = ((const float4*)bias)[e4];

        float4 r;
        r.x = p0 * w0.x + p1 * w1.x + p2 * w2.x + bb.x;
        r.y = p0 * w0.y + p1 * w1.y + p2 * w2.y + bb.y;
        r.z = p0 * w0.z + p1 * w1.z + p2 * w2.z + bb.z;
        r.w = p0 * w0.w + p1 * w1.w + p2 * w2.w + bb.w;
        ((float4*)out)[(size_t)(batch * Kn + k0 + kk) * (En / 4) + e4] = r;
    }
}

extern "C" void kernel_launch(void* const* d_in, const int* in_sizes, int n_in,
                              void* d_out, int out_size, void* d_ws, size_t ws_size,
                              hipStream_t stream) {
    const float* img  = (const float*)d_in[0];  // (4,3,224,224) fp32
    const int*   seg  = (const int*)  d_in[1];  // (4,224,224) int32
    const float* Wm   = (const float*)d_in[2];  // (3,768) fp32
    const float* bias = (const float*)d_in[3];  // (768,) fp32
    float* out = (float*)d_out;                 // (4,196,768) fp32
    float* ws  = (float*)d_ws;                  // partials + padded tags

    fused_kernel<<<NPOOL, 256, 0, stream>>>(img, seg, Wm, bias, out, ws);
}